// Round 8
// baseline (209.095 us; speedup 1.0000x reference)
//
#include <hip/hip_runtime.h>
#include <hip/hip_bf16.h>

#define DEV __device__ __forceinline__

typedef __bf16 bf16x8 __attribute__((ext_vector_type(8)));
typedef float  f32x4  __attribute__((ext_vector_type(4)));
typedef float  f32x16 __attribute__((ext_vector_type(16)));
typedef unsigned u32x4 __attribute__((ext_vector_type(4)));
typedef unsigned short u16;

static constexpr float LOG2E = 1.44269504088896340736f;

// fp32 -> bf16 round-to-nearest-even (scalar)
DEV u16 f2bf(float f) {
    unsigned u = __float_as_uint(f);
    u += 0x7fffu + ((u >> 16) & 1u);
    return (u16)(u >> 16);
}

// pack 2 fp32 -> 2 bf16 in one v_perm (round-half-up)
DEV unsigned pack_rn(float a, float b) {
    unsigned ua = __float_as_uint(a) + 0x8000u;
    unsigned ub = __float_as_uint(b) + 0x8000u;
    return __builtin_amdgcn_perm(ub, ua, 0x07060302u);  // [ub.hi16 : ua.hi16]
}

// pack 2 fp32 -> 2 bf16 in one instruction (a -> low 16)
DEV unsigned cvtpk(float lo, float hi) {
    unsigned r;
    asm("v_cvt_pk_bf16_f32 %0, %1, %2" : "=v"(r) : "v"(lo), "v"(hi));
    return r;
}

// v_permlane32_swap: ret[0] = [a@0..31 | b@0..31], ret[1] = [a@32..63 | b@32..63]
DEV auto plswap(unsigned a, unsigned b) {
    return __builtin_amdgcn_permlane32_swap(a, b, false, false);
}

typedef const __attribute__((address_space(1))) void* gas_ptr;
typedef __attribute__((address_space(3))) void* las_ptr;

// async global->LDS, 16B per lane. LDS dest = wave-uniform base + lane*16.
DEV void async16(const void* g, void* l) {
    __builtin_amdgcn_global_load_lds((gas_ptr)g, (las_ptr)l, 16, 0, 0);
}

// ---------------- convert fp32 -> bf16 (7 tensors via blockIdx.z) -------------
__global__ __launch_bounds__(256)
void convert_all(const float* q, const float* k, const float* v,
                 const float* wq, const float* wk, const float* wv, const float* wo,
                 u16* oq, u16* ok, u16* ov, u16* owq, u16* owk, u16* owv, u16* owo)
{
    const float* src; u16* dst; int n;
    switch (blockIdx.z) {
        case 0: src = q;  dst = oq;  n = 4194304; break;
        case 1: src = k;  dst = ok;  n = 4194304; break;
        case 2: src = v;  dst = ov;  n = 4194304; break;
        case 3: src = wq; dst = owq; n = 1048576; break;
        case 4: src = wk; dst = owk; n = 1048576; break;
        case 5: src = wv; dst = owv; n = 1048576; break;
        default: src = wo; dst = owo; n = 1048576; break;
    }
    int n4 = n >> 2;
    int stride = gridDim.x * blockDim.x;
    for (int i = blockIdx.x * blockDim.x + threadIdx.x; i < n4; i += stride) {
        float4 f = ((const float4*)src)[i];
        uint2 o;
        o.x = pack_rn(f.x, f.y);
        o.y = pack_rn(f.z, f.w);
        ((uint2*)dst)[i] = o;
    }
}

// ------------- 128x128 bf16 GEMM, BK=32 THREE-buffer counted-vmcnt core -------
// R7-verified: stage K-step kk+2 into buf (kk+2)%3, s_waitcnt vmcnt(4) + raw
// s_barrier per body (never 0 in the main loop). Read->overwrite separation is
// 1 barrier (standard double-buffer argument). LDS 48KB -> 3 blocks/CU.
// Swizzle: LDS[r][c] = global[r][c ^ xr(r)], xr(r) = (r&3)^((r>>2)&3),
// both-sides (rule #21).
DEV void gemm128_pipe3(const u16* __restrict__ A, const u16* __restrict__ B,
                       int rowBase, int colBase, u16 (*Sm)[8192], f32x4 acc[4][4])
{
    const int tid = threadIdx.x;
    const int w = tid >> 6, l = tid & 63;
    const int lr = l & 15, lq = l >> 4;
    const int wr0 = (w >> 1) * 64, wc0 = (w & 1) * 64;
    const int xr = (lr & 3) ^ ((lr >> 2) & 3);
    const int swc = ((l & 3) ^ ((l >> 2) & 3) ^ (l >> 4)) * 8;
    const int ci0 = w * 2, ci1 = w * 2 + 1;
    const u16* a0 = A + (size_t)(rowBase + ci0 * 16 + (l >> 2)) * 1024 + swc;
    const u16* a1 = A + (size_t)(rowBase + ci1 * 16 + (l >> 2)) * 1024 + swc;
    const u16* b0 = B + (size_t)(colBase + ci0 * 16 + (l >> 2)) * 1024 + swc;
    const u16* b1 = B + (size_t)(colBase + ci1 * 16 + (l >> 2)) * 1024 + swc;

#pragma unroll
    for (int i = 0; i < 4; ++i)
#pragma unroll
        for (int j = 0; j < 4; ++j) acc[i][j] = (f32x4){0.f, 0.f, 0.f, 0.f};

    // prologue: stage K-steps 0 (buf0) and 1 (buf1); 8 loads/lane
    async16(a0,      &Sm[0][ci0 * 512]);
    async16(b0,      &Sm[0][4096 + ci0 * 512]);
    async16(a1,      &Sm[0][ci1 * 512]);
    async16(b1,      &Sm[0][4096 + ci1 * 512]);
    async16(a0 + 32, &Sm[1][ci0 * 512]);
    async16(b0 + 32, &Sm[1][4096 + ci0 * 512]);
    async16(a1 + 32, &Sm[1][ci1 * 512]);
    async16(b1 + 32, &Sm[1][4096 + ci1 * 512]);
    a0 += 64; a1 += 64; b0 += 64; b1 += 64;
    asm volatile("s_waitcnt vmcnt(4)" ::: "memory");   // step 0 landed
    __builtin_amdgcn_s_barrier();
    __builtin_amdgcn_sched_barrier(0);

    // body kk (BUF = kk%3): stage kk+2 -> (BUF+2)%3; 8 ds_read + 16 MFMA;
    // vmcnt(4)+barrier confirms step kk+1 for the next body.
#define GEMM_BODY(BUFI, DO_STAGE, WAITK) do {                                        \
        constexpr int BUF_ = (BUFI);                                                 \
        constexpr int TGT_ = (BUF_ + 2) % 3;                                         \
        if (DO_STAGE) {                                                              \
            async16(a0, &Sm[TGT_][ci0 * 512]);                                       \
            async16(b0, &Sm[TGT_][4096 + ci0 * 512]);                                \
            async16(a1, &Sm[TGT_][ci1 * 512]);                                       \
            async16(b1, &Sm[TGT_][4096 + ci1 * 512]);                                \
            a0 += 32; a1 += 32; b0 += 32; b1 += 32;                                  \
        }                                                                            \
        const char* Ab_ = (const char*)&Sm[BUF_][0];                                 \
        const char* Bb_ = (const char*)&Sm[BUF_][4096];                              \
        bf16x8 af[4], bg[4];                                                         \
        _Pragma("unroll")                                                            \
        for (int i = 0; i < 4; ++i)                                                  \
            af[i] = *(const bf16x8*)(Ab_ + (wr0 + i * 16 + lr) * 64 + ((lq ^ xr) * 16)); \
        _Pragma("unroll")                                                            \
        for (int j = 0; j < 4; ++j)                                                  \
            bg[j] = *(const bf16x8*)(Bb_ + (wc0 + j * 16 + lr) * 64 + ((lq ^ xr) * 16)); \
        _Pragma("unroll")                                                            \
        for (int i = 0; i < 4; ++i)                                                  \
            _Pragma("unroll")                                                        \
            for (int j = 0; j < 4; ++j)                                              \
                acc[i][j] = __builtin_amdgcn_mfma_f32_16x16x32_bf16(af[i], bg[j], acc[i][j], 0, 0, 0); \
        if ((WAITK) == 0) {                                                          \
            asm volatile("s_waitcnt vmcnt(4)" ::: "memory");                         \
            __builtin_amdgcn_s_barrier();                                            \
            __builtin_amdgcn_sched_barrier(0);                                       \
        } else if ((WAITK) == 1) {                                                   \
            asm volatile("s_waitcnt vmcnt(0)" ::: "memory");                         \
            __builtin_amdgcn_s_barrier();                                            \
            __builtin_amdgcn_sched_barrier(0);                                       \
        }                                                                            \
    } while (0)

    // kk = 0..29: ten groups of 3 (last stage at kk=29 targets step 31)
    for (int g = 0; g < 10; ++g) {
        GEMM_BODY(0, true, 0);
        GEMM_BODY(1, true, 0);
        GEMM_BODY(2, true, 0);
    }
    GEMM_BODY(0, false, 1);   // kk=30, drain (step 31 lands)
    GEMM_BODY(1, false, 2);   // kk=31, no barrier
#undef GEMM_BODY
}

// --------- QKV projection: X[4096,1024] @ W^T -> [B,H,S,D] bf16 ---------------
// Q output (z==0) pre-scaled by LOG2E so attention softmax is a raw exp2.
__global__ __launch_bounds__(256, 3)
void proj_gemm(const u16* __restrict__ Xq, const u16* __restrict__ Xk, const u16* __restrict__ Xv,
               const u16* __restrict__ Wq, const u16* __restrict__ Wk, const u16* __restrict__ Wv,
               u16* __restrict__ Qo, u16* __restrict__ Ko, u16* __restrict__ Vo)
{
    __shared__ __align__(16) u16 Sm[3][8192];   // 48KB: 3 bufs x [A 8KB | B 8KB]
    const u16* A; const u16* W; u16* C; float scale;
    if (blockIdx.z == 0)      { A = Xq; W = Wq; C = Qo; scale = LOG2E; }
    else if (blockIdx.z == 1) { A = Xk; W = Wk; C = Ko; scale = 1.0f; }
    else                      { A = Xv; W = Wv; C = Vo; scale = 1.0f; }

    f32x4 acc[4][4];
    gemm128_pipe3(A, W, blockIdx.y * 128, blockIdx.x * 128, Sm, acc);

    const int tid = threadIdx.x, w = tid >> 6, l = tid & 63;
    const int lr = l & 15, lq = l >> 4;
    const int r0 = blockIdx.y * 128 + (w >> 1) * 64;
    const int c0 = blockIdx.x * 128 + (w & 1) * 64;
#pragma unroll
    for (int i = 0; i < 4; ++i)
#pragma unroll
        for (int j = 0; j < 4; ++j)
#pragma unroll
            for (int r = 0; r < 4; ++r) {
                int row = r0 + i * 16 + lq * 4 + r;   // X row = s*2 + b
                int col = c0 + j * 16 + lr;           // n = h*64 + d
                int s = row >> 1, b = row & 1, h = col >> 6, d = col & 63;
                C[(size_t)((b * 16 + h) * 2048 + s) * 64 + d] = f2bf(acc[i][j][r] * scale);
            }
}

// --------- V transpose: [B,H,S,D] -> [B,H,D,S] bf16 ---------------------------
__global__ __launch_bounds__(256)
void transpose_v(const u16* __restrict__ Vin, u16* __restrict__ Vout)
{
    __shared__ u16 T[64][72];
    const int bh = blockIdx.y;
    const int s0 = blockIdx.x * 64;
    const int t = threadIdx.x;
    const size_t base = (size_t)bh * 2048 * 64;
    const int row = t >> 3, cc = (t & 7) * 8;
#pragma unroll
    for (int i = 0; i < 2; ++i) {
        int r = i * 32 + row;
        uint4 v = *(const uint4*)&Vin[base + (size_t)(s0 + r) * 64 + cc];
        u16* p = (u16*)&v;
#pragma unroll
        for (int j = 0; j < 8; ++j) T[r][cc + j] = p[j];
    }
    __syncthreads();
#pragma unroll
    for (int i = 0; i < 2; ++i) {
        int d = i * 32 + row;
        alignas(16) u16 tmp[8];
#pragma unroll
        for (int j = 0; j < 8; ++j) tmp[j] = T[cc + j][d];
        *(uint4*)&Vout[base + (size_t)d * 2048 + s0 + cc] = *(const uint4*)tmp;
    }
}

// --------- flash attention v9 (R3/R6-verified, 43.8us): quad-buffer, counted --
// vmcnt, static addresses. 4 waves x 32 q-rows = Q-tile 128; KV tile 64; FOUR
// buffers (64KB LDS), prefetch 2 tiles ahead, one raw s_barrier per kt with
// s_waitcnt vmcnt(4) (never 0 in the main loop). Zf-seed experiment (R7, +6us)
// reverted: per-kt S[2] = {} init restored (compiler's accvgpr init is faster
// than a long-lived zero C operand -- measured A/B, R6 43.8 vs R7 49.7).
__global__ __launch_bounds__(256, 2)
void attn_kernel(const u16* __restrict__ Qg, const u16* __restrict__ Kg,
                 const u16* __restrict__ Vtg, u16* __restrict__ attn)
{
    __shared__ __align__(16) u16 KV[4][8192];      // [buf][ K tile 8KB | V^T tile 8KB ]

    const int tid = threadIdx.x, w = tid >> 6, l = tid & 63;
    const int q = l & 31, hi = l >> 5;
    const int swz = (q & 7) ^ ((q >> 3) & 3);       // read-side XOR (row bits 0..4)
    const int srow = l >> 3;

    // XCD-aware remap: grid 16x32 = 512 blocks; xcd = lin&7; 4 bh per xcd, 16 q-blocks/bh
    const int lin = blockIdx.x + (blockIdx.y << 4);   // gridDim.x == 16
    const int grp = lin >> 3;                          // [0,64)
    const int bh  = (lin & 7) * 4 + (grp >> 4);
    const int q0  = (grp & 15) * 128;
    const size_t base = (size_t)bh * 2048 * 64;

    // per-lane LDS read base (bytes): row q within a 64x64 tile, column slot kd
    int ra[4];
#pragma unroll
    for (int kd = 0; kd < 4; ++kd)
        ra[kd] = q * 128 + (((kd * 2 + hi) ^ swz) * 16);

    // prologue staging: Q(128x64 = 16KB) -> KV[3]; K0/V0 -> KV[0]; K1/V1 -> KV[1]
#pragma unroll
    for (int c = 0; c < 4; ++c) {
        int ci = w * 4 + c, row = ci * 8 + srow;
        int swcol = ((l & 7) ^ (l >> 3) ^ (ci & 3)) * 8;
        async16(&Qg[base + (size_t)(q0 + row) * 64 + swcol], &KV[3][ci * 512]);
    }
#pragma unroll
    for (int t = 0; t < 2; ++t)
#pragma unroll
        for (int c = 0; c < 2; ++c) {
            int ci = w * 2 + c, row = ci * 8 + srow;
            int swcol = ((l & 7) ^ (l >> 3) ^ (ci & 3)) * 8;
            async16(&Kg[base + (size_t)(t * 64 + row) * 64 + swcol], &KV[t][ci * 512]);
            async16(&Vtg[base + (size_t)row * 2048 + t * 64 + swcol], &KV[t][4096 + ci * 512]);
        }

    // walking staging pointers, positioned for tile 2
    const int row0 = (w * 2 + 0) * 8 + srow, row1 = (w * 2 + 1) * 8 + srow;
    const int sw0 = ((l & 7) ^ (l >> 3) ^ ((w * 2 + 0) & 3)) * 8;
    const int sw1 = ((l & 7) ^ (l >> 3) ^ ((w * 2 + 1) & 3)) * 8;
    const u16* kp0 = Kg + base + (size_t)(128 + row0) * 64 + sw0;
    const u16* kp1 = Kg + base + (size_t)(128 + row1) * 64 + sw1;
    const u16* vp0 = Vtg + base + (size_t)row0 * 2048 + 128 + sw0;
    const u16* vp1 = Vtg + base + (size_t)row1 * 2048 + 128 + sw1;

    // Q + K0/V0 landed (leaves K1/V1's 4 in flight); then block-wide visible
    asm volatile("s_waitcnt vmcnt(4)" ::: "memory");
    __builtin_amdgcn_s_barrier();
    __builtin_amdgcn_sched_barrier(0);

    // hoist Q fragments from KV[3]: row w*32+q, slot kd
    bf16x8 bq[4];
    {
        const char* Qb_ = (const char*)&KV[3][0];
#pragma unroll
        for (int kd = 0; kd < 4; ++kd)
            bq[kd] = *(const bf16x8*)(Qb_ + w * 4096 + ra[kd]);
    }

    f32x16 O[2] = {};  // O^T: [d-tile nt][q = lane&31]; d = nt*32 + (r&3)+8*(r>>2)+4*hi
    float l0 = 0.f, l1 = 0.f, l2 = 0.f, l3 = 0.f;

    // one kt step. BUFI static (kt&3); DO_ISSUE stages kt+2 into (BUFI+2)&3;
    // WAITK: 0 = vmcnt(4)+barrier, 1 = vmcnt(0)+barrier, 2 = none (last)
#define ATTN_STEP(BUFI, DO_ISSUE, WAITK) do {                                        \
        constexpr int BUF_ = (BUFI);                                                 \
        constexpr int TGT_ = (BUF_ + 2) & 3;                                         \
        if (DO_ISSUE) {                                                              \
            async16(kp0, &KV[TGT_][(w * 2 + 0) * 512]);                              \
            async16(vp0, &KV[TGT_][4096 + (w * 2 + 0) * 512]);                       \
            async16(kp1, &KV[TGT_][(w * 2 + 1) * 512]);                              \
            async16(vp1, &KV[TGT_][4096 + (w * 2 + 1) * 512]);                       \
            kp0 += 4096; kp1 += 4096; vp0 += 64; vp1 += 64;                          \
        }                                                                            \
        const char* Kb_ = (const char*)&KV[BUF_][0];                                 \
        const char* Vb_ = (const char*)&KV[BUF_][4096];                              \
        f32x16 S[2] = {};                                                            \
        _Pragma("unroll")                                                            \
        for (int mt = 0; mt < 2; ++mt)                                               \
            _Pragma("unroll")                                                        \
            for (int kd = 0; kd < 4; ++kd) {                                         \
                bf16x8 ak = *(const bf16x8*)(Kb_ + mt * 4096 + ra[kd]);              \
                S[mt] = __builtin_amdgcn_mfma_f32_32x32x16_bf16(ak, bq[kd], S[mt], 0, 0, 0); \
            }                                                                        \
        _Pragma("unroll")                                                            \
        for (int mt = 0; mt < 2; ++mt)                                               \
            _Pragma("unroll")                                                        \
            for (int r = 0; r < 16; r += 4) {                                        \
                S[mt][r+0] = __builtin_amdgcn_exp2f(S[mt][r+0]); l0 += S[mt][r+0];   \
                S[mt][r+1] = __builtin_amdgcn_exp2f(S[mt][r+1]); l1 += S[mt][r+1];   \
                S[mt][r+2] = __builtin_amdgcn_exp2f(S[mt][r+2]); l2 += S[mt][r+2];   \
                S[mt][r+3] = __builtin_amdgcn_exp2f(S[mt][r+3]); l3 += S[mt][r+3];   \
            }                                                                        \
        bf16x8 bp[4];                                                                \
        _Pragma("unroll")                                                            \
        for (int mt = 0; mt < 2; ++mt) {                                             \
            unsigned W0 = cvtpk(S[mt][0],  S[mt][1]);                                \
            unsigned W1 = cvtpk(S[mt][2],  S[mt][3]);                                \
            unsigned W2 = cvtpk(S[mt][4],  S[mt][5]);                                \
            unsigned W3 = cvtpk(S[mt][6],  S[mt][7]);                                \
            unsigned W4 = cvtpk(S[mt][8],  S[mt][9]);                                \
            unsigned W5 = cvtpk(S[mt][10], S[mt][11]);                               \
            unsigned W6 = cvtpk(S[mt][12], S[mt][13]);                               \
            unsigned W7 = cvtpk(S[mt][14], S[mt][15]);                               \
            auto a0 = plswap(W0, W2);                                                \
            auto a1 = plswap(W1, W3);                                                \
            auto a2 = plswap(W4, W6);                                                \
            auto a3 = plswap(W5, W7);                                                \
            u32x4 lo4 = {(unsigned)a0[0], (unsigned)a1[0], (unsigned)a0[1], (unsigned)a1[1]}; \
            u32x4 hi4 = {(unsigned)a2[0], (unsigned)a3[0], (unsigned)a2[1], (unsigned)a3[1]}; \
            bp[2*mt+0] = __builtin_bit_cast(bf16x8, lo4);                            \
            bp[2*mt+1] = __builtin_bit_cast(bf16x8, hi4);                            \
        }                                                                            \
        _Pragma("unroll")                                                            \
        for (int nt = 0; nt < 2; ++nt)                                               \
            _Pragma("unroll")                                                        \
            for (int ks = 0; ks < 4; ++ks) {                                         \
                bf16x8 av = *(const bf16x8*)(Vb_ + nt * 4096 + ra[ks]);              \
                O[nt] = __builtin_amdgcn_mfma_f32_32x32x16_bf16(av, bp[ks], O[nt], 0, 0, 0); \
            }                                                                        \
        if ((WAITK) == 0) {                                                          \
            asm volatile("s_waitcnt vmcnt(4)" ::: "memory");                         \
            __builtin_amdgcn_s_barrier();                                            \
            __builtin_amdgcn_sched_barrier(0);                                       \
        } else if ((WAITK) == 1) {                                                   \
            asm volatile("s_waitcnt vmcnt(0)" ::: "memory");                         \
            __builtin_amdgcn_s_barrier();                                            \
            __builtin_amdgcn_sched_barrier(0);                                       \
        }                                                                            \
    } while (0)

    for (int kt4 = 0; kt4 < 28; kt4 += 4) {
        ATTN_STEP(0, true, 0);
        ATTN_STEP(1, true, 0);
        ATTN_STEP(2, true, 0);
        ATTN_STEP(3, true, 0);
    }
    // tail: kt = 28..31 (kt=28 stages kt=30; kt=29 stages kt=31; then drain)
    ATTN_STEP(0, true, 0);
    ATTN_STEP(1, true, 0);
    ATTN_STEP(2, false, 1);
    ATTN_STEP(3, false, 2);
#undef ATTN_STEP

    // final softmax denominator: lane sum -> cross-half reduce (once, not per kt)
    float rs = (l0 + l1) + (l2 + l3);
    {
        auto t = plswap(__float_as_uint(rs), __float_as_uint(rs));
        rs = __uint_as_float((unsigned)t[0]) + __uint_as_float((unsigned)t[1]);
    }
    const float inv = 1.f / rs;

    // epilogue: lane holds q = l&31 -> s = q0 + w*32 + q; d = nt*32 + u*8 + hi*4 + e
    const int b = bh >> 4, h = bh & 15;
    const int s = q0 + w * 32 + q;
    u16* orow = &attn[(size_t)(s * 2 + b) * 1024 + h * 64];
#pragma unroll
    for (int nt = 0; nt < 2; ++nt)
#pragma unroll
        for (int u = 0; u < 4; ++u) {
            uint2 pk;
            pk.x = pack_rn(O[nt][4*u+0] * inv, O[nt][4*u+1] * inv);
            pk.y = pack_rn(O[nt][4*u+2] * inv, O[nt][4*u+3] * inv);
            *(uint2*)&orow[nt * 32 + u * 8 + hi * 4] = pk;
        }
}

// --------- output projection: attn[4096,1024] @ Wo^T -> fp32 out --------------
// 128x64 tile, 128 threads (2 waves), 3-buffer BK=32 counted-vmcnt pipe
// (same skeleton as gemm128_pipe3; 6 loads/body -> vmcnt(6)). LDS 36KB.
// R7-verified.
__global__ __launch_bounds__(128)
void out_gemm(const u16* __restrict__ A, const u16* __restrict__ W, float* __restrict__ out)
{
    __shared__ __align__(16) u16 Sm[3][6144];   // 3 bufs x [A 8KB | B 4KB]
    const int tid = threadIdx.x;
    const int w = tid >> 6, l = tid & 63;
    const int lr = l & 15, lq = l >> 4;
    const int xr = (lr & 3) ^ ((lr >> 2) & 3);
    const int swc = ((l & 3) ^ ((l >> 2) & 3) ^ (l >> 4)) * 8;
    const int rowBase = blockIdx.y * 128;
    const int colBase = blockIdx.x * 64;

    const u16* ap0 = A + (size_t)(rowBase + (w * 4 + 0) * 16 + (l >> 2)) * 1024 + swc;
    const u16* ap1 = A + (size_t)(rowBase + (w * 4 + 1) * 16 + (l >> 2)) * 1024 + swc;
    const u16* ap2 = A + (size_t)(rowBase + (w * 4 + 2) * 16 + (l >> 2)) * 1024 + swc;
    const u16* ap3 = A + (size_t)(rowBase + (w * 4 + 3) * 16 + (l >> 2)) * 1024 + swc;
    const u16* bp0 = W + (size_t)(colBase + (w * 2 + 0) * 16 + (l >> 2)) * 1024 + swc;
    const u16* bp1 = W + (size_t)(colBase + (w * 2 + 1) * 16 + (l >> 2)) * 1024 + swc;

    f32x4 acc[4][4];
#pragma unroll
    for (int i = 0; i < 4; ++i)
#pragma unroll
        for (int j = 0; j < 4; ++j) acc[i][j] = (f32x4){0.f, 0.f, 0.f, 0.f};

    // prologue: stage K-steps 0 (buf0) and 1 (buf1); 12 loads/lane
    async16(ap0,      &Sm[0][(w * 4 + 0) * 512]);
    async16(ap1,      &Sm[0][(w * 4 + 1) * 512]);
    async16(ap2,      &Sm[0][(w * 4 + 2) * 512]);
    async16(ap3,      &Sm[0][(w * 4 + 3) * 512]);
    async16(bp0,      &Sm[0][4096 + (w * 2 + 0) * 512]);
    async16(bp1,      &Sm[0][4096 + (w * 2 + 1) * 512]);
    async16(ap0 + 32, &Sm[1][(w * 4 + 0) * 512]);
    async16(ap1 + 32, &Sm[1][(w * 4 + 1) * 512]);
    async16(ap2 + 32, &Sm[1][(w * 4 + 2) * 512]);
    async16(ap3 + 32, &Sm[1][(w * 4 + 3) * 512]);
    async16(bp0 + 32, &Sm[1][4096 + (w * 2 + 0) * 512]);
    async16(bp1 + 32, &Sm[1][4096 + (w * 2 + 1) * 512]);
    ap0 += 64; ap1 += 64; ap2 += 64; ap3 += 64; bp0 += 64; bp1 += 64;
    asm volatile("s_waitcnt vmcnt(6)" ::: "memory");   // step 0 landed
    __builtin_amdgcn_s_barrier();
    __builtin_amdgcn_sched_barrier(0);

#define OUT_BODY(BUFI, DO_STAGE, WAITK) do {                                         \
        constexpr int BUF_ = (BUFI);                                                 \
        constexpr int TGT_ = (BUF_ + 2) % 3;                                         \
        if (DO_STAGE) {                                                              \
            async16(ap0, &Sm[TGT_][(w * 4 + 0) * 512]);                              \
            async16(ap1, &Sm[TGT_][(w * 4 + 1) * 512]);                              \
            async16(ap2, &Sm[TGT_][(w * 4 + 2) * 512]);                              \
            async16(ap3, &Sm[TGT_][(w * 4 + 3) * 512]);                              \
            async16(bp0, &Sm[TGT_][4096 + (w * 2 + 0) * 512]);                       \
            async16(bp1, &Sm[TGT_][4096 + (w * 2 + 1) * 512]);                       \
            ap0 += 32; ap1 += 32; ap2 += 32; ap3 += 32; bp0 += 32; bp1 += 32;        \
        }                                                                            \
        const char* Ab_ = (const char*)&Sm[BUF_][0];                                 \
        const char* Bb_ = (const char*)&Sm[BUF_][4096];                              \
        bf16x8 af[4], bg[4];                                                         \
        _Pragma("unroll")                                                            \
        for (int i = 0; i < 4; ++i)                                                  \
            af[i] = *(const bf16x8*)(Ab_ + (w * 64 + i * 16 + lr) * 64 + ((lq ^ xr) * 16)); \
        _Pragma("unroll")                                                            \
        for (int j = 0; j < 4; ++j)                                                  \
            bg[j] = *(const bf16x8*)(Bb_ + (j * 16 + lr) * 64 + ((lq ^ xr) * 16));   \
        _Pragma("unroll")                                                            \
        for (int i = 0; i < 4; ++i)                                                  \
            _Pragma("unroll")                                                        \
            for (int j = 0; j < 4; ++j)                                              \
                acc[i][j] = __builtin_amdgcn_mfma_f32_16x16x32_bf16(af[i], bg[j], acc[i][j], 0, 0, 0); \
        if ((WAITK) == 0) {                                                          \
            asm volatile("s_waitcnt vmcnt(6)" ::: "memory");                         \
            __builtin_amdgcn_s_barrier();                                            \
            __builtin_amdgcn_sched_barrier(0);                                       \
        } else if ((WAITK) == 1) {                                                   \
            asm volatile("s_waitcnt vmcnt(0)" ::: "memory");                         \
            __builtin_amdgcn_s_barrier();                                            \
            __builtin_amdgcn_sched_barrier(0);                                       \
        }                                                                            \
    } while (0)

    for (int g = 0; g < 10; ++g) {
        OUT_BODY(0, true, 0);
        OUT_BODY(1, true, 0);
        OUT_BODY(2, true, 0);
    }
    OUT_BODY(0, false, 1);   // kk=30, drain (step 31 lands)
    OUT_BODY(1, false, 2);   // kk=31, no barrier
#undef OUT_BODY

    const int r0 = rowBase + w * 64;
#pragma unroll
    for (int i = 0; i < 4; ++i)
#pragma unroll
        for (int j = 0; j < 4; ++j)
#pragma unroll
            for (int r = 0; r < 4; ++r)
                out[(size_t)(r0 + i * 16 + lq * 4 + r) * 1024 + (colBase + j * 16 + lr)] = acc[i][j][r];
}

extern "C" void kernel_launch(void* const* d_in, const int* in_sizes, int n_in,
                              void* d_out, int out_size, void* d_ws, size_t ws_size,
                              hipStream_t stream)
{
    const float* q  = (const float*)d_in[0];
    const float* k  = (const float*)d_in[1];
    const float* v  = (const float*)d_in[2];
    const float* Wq = (const float*)d_in[3];
    const float* Wk = (const float*)d_in[4];
    const float* Wv = (const float*)d_in[5];
    const float* Wo = (const float*)d_in[6];

    // workspace layout (u16 elements); needs 58,720,256 bytes.
    u16* ws   = (u16*)d_ws;
    u16* Xq   = ws;              // 4M elems
    u16* Xk   = ws + 4194304;
    u16* Xv   = ws + 8388608;
    u16* Wqb  = ws + 12582912;   // 1M each
    u16* Wkb  = ws + 13631488;
    u16* Wvb  = ws + 14680064;
    u16* Wob  = ws + 15728640;
    u16* Qb   = ws + 16777216;   // 4M each
    u16* Kb   = ws + 20971520;
    u16* Vtmp = ws + 25165824;
    u16* Vt   = Xq;   // alias: Xq dead after proj_gemm
    u16* At   = Xk;   // alias: Xk dead after proj_gemm

    convert_all<<<dim3(512, 1, 7), 256, 0, stream>>>(q, k, v, Wq, Wk, Wv, Wo,
                                                     Xq, Xk, Xv, Wqb, Wkb, Wvb, Wob);
    proj_gemm<<<dim3(8, 32, 3), 256, 0, stream>>>(Xq, Xk, Xv, Wqb, Wkb, Wvb, Qb, Kb, Vtmp);
    transpose_v<<<dim3(32, 32), 256, 0, stream>>>(Vtmp, Vt);
    attn_kernel<<<dim3(16, 32), 256, 0, stream>>>(Qb, Kb, Vt, At);
    out_gemm<<<dim3(16, 32), 128, 0, stream>>>(At, Wob, (float*)d_out);
}

// Round 9
// 202.566 us; speedup vs baseline: 1.0322x; 1.0322x over previous
//
#include <hip/hip_runtime.h>
#include <hip/hip_bf16.h>

#define DEV __device__ __forceinline__

typedef __bf16 bf16x8 __attribute__((ext_vector_type(8)));
typedef float  f32x4  __attribute__((ext_vector_type(4)));
typedef float  f32x16 __attribute__((ext_vector_type(16)));
typedef unsigned u32x4 __attribute__((ext_vector_type(4)));
typedef unsigned short u16;

static constexpr float LOG2E = 1.44269504088896340736f;

// fp32 -> bf16 round-to-nearest-even (scalar)
DEV u16 f2bf(float f) {
    unsigned u = __float_as_uint(f);
    u += 0x7fffu + ((u >> 16) & 1u);
    return (u16)(u >> 16);
}

// pack 2 fp32 -> 2 bf16 in one v_perm (round-half-up)
DEV unsigned pack_rn(float a, float b) {
    unsigned ua = __float_as_uint(a) + 0x8000u;
    unsigned ub = __float_as_uint(b) + 0x8000u;
    return __builtin_amdgcn_perm(ub, ua, 0x07060302u);  // [ub.hi16 : ua.hi16]
}

// pack 2 fp32 -> 2 bf16 in one instruction (a -> low 16)
DEV unsigned cvtpk(float lo, float hi) {
    unsigned r;
    asm("v_cvt_pk_bf16_f32 %0, %1, %2" : "=v"(r) : "v"(lo), "v"(hi));
    return r;
}

// v_permlane32_swap: ret[0] = [a@0..31 | b@0..31], ret[1] = [a@32..63 | b@32..63]
DEV auto plswap(unsigned a, unsigned b) {
    return __builtin_amdgcn_permlane32_swap(a, b, false, false);
}

typedef const __attribute__((address_space(1))) void* gas_ptr;
typedef __attribute__((address_space(3))) void* las_ptr;

// async global->LDS, 16B per lane. LDS dest = wave-uniform base + lane*16.
DEV void async16(const void* g, void* l) {
    __builtin_amdgcn_global_load_lds((gas_ptr)g, (las_ptr)l, 16, 0, 0);
}

// ---------------- convert fp32 -> bf16 (7 tensors via blockIdx.z) -------------
__global__ __launch_bounds__(256)
void convert_all(const float* q, const float* k, const float* v,
                 const float* wq, const float* wk, const float* wv, const float* wo,
                 u16* oq, u16* ok, u16* ov, u16* owq, u16* owk, u16* owv, u16* owo)
{
    const float* src; u16* dst; int n;
    switch (blockIdx.z) {
        case 0: src = q;  dst = oq;  n = 4194304; break;
        case 1: src = k;  dst = ok;  n = 4194304; break;
        case 2: src = v;  dst = ov;  n = 4194304; break;
        case 3: src = wq; dst = owq; n = 1048576; break;
        case 4: src = wk; dst = owk; n = 1048576; break;
        case 5: src = wv; dst = owv; n = 1048576; break;
        default: src = wo; dst = owo; n = 1048576; break;
    }
    int n4 = n >> 2;
    int stride = gridDim.x * blockDim.x;
    for (int i = blockIdx.x * blockDim.x + threadIdx.x; i < n4; i += stride) {
        float4 f = ((const float4*)src)[i];
        uint2 o;
        o.x = pack_rn(f.x, f.y);
        o.y = pack_rn(f.z, f.w);
        ((uint2*)dst)[i] = o;
    }
}

// ------------- 128x128 bf16 GEMM, BK=32 THREE-buffer counted-vmcnt core -------
// R7/R8-verified: stage K-step kk+2 into buf (kk+2)%3, s_waitcnt vmcnt(4) + raw
// s_barrier per body (never 0 in the main loop). Read->overwrite separation is
// 1 barrier (standard double-buffer argument). LDS 48KB -> 3 blocks/CU.
// Swizzle: LDS[r][c] = global[r][c ^ xr(r)], xr(r) = (r&3)^((r>>2)&3),
// both-sides (rule #21).
DEV void gemm128_pipe3(const u16* __restrict__ A, const u16* __restrict__ B,
                       int rowBase, int colBase, u16 (*Sm)[8192], f32x4 acc[4][4])
{
    const int tid = threadIdx.x;
    const int w = tid >> 6, l = tid & 63;
    const int lr = l & 15, lq = l >> 4;
    const int wr0 = (w >> 1) * 64, wc0 = (w & 1) * 64;
    const int xr = (lr & 3) ^ ((lr >> 2) & 3);
    const int swc = ((l & 3) ^ ((l >> 2) & 3) ^ (l >> 4)) * 8;
    const int ci0 = w * 2, ci1 = w * 2 + 1;
    const u16* a0 = A + (size_t)(rowBase + ci0 * 16 + (l >> 2)) * 1024 + swc;
    const u16* a1 = A + (size_t)(rowBase + ci1 * 16 + (l >> 2)) * 1024 + swc;
    const u16* b0 = B + (size_t)(colBase + ci0 * 16 + (l >> 2)) * 1024 + swc;
    const u16* b1 = B + (size_t)(colBase + ci1 * 16 + (l >> 2)) * 1024 + swc;

#pragma unroll
    for (int i = 0; i < 4; ++i)
#pragma unroll
        for (int j = 0; j < 4; ++j) acc[i][j] = (f32x4){0.f, 0.f, 0.f, 0.f};

    // prologue: stage K-steps 0 (buf0) and 1 (buf1); 8 loads/lane
    async16(a0,      &Sm[0][ci0 * 512]);
    async16(b0,      &Sm[0][4096 + ci0 * 512]);
    async16(a1,      &Sm[0][ci1 * 512]);
    async16(b1,      &Sm[0][4096 + ci1 * 512]);
    async16(a0 + 32, &Sm[1][ci0 * 512]);
    async16(b0 + 32, &Sm[1][4096 + ci0 * 512]);
    async16(a1 + 32, &Sm[1][ci1 * 512]);
    async16(b1 + 32, &Sm[1][4096 + ci1 * 512]);
    a0 += 64; a1 += 64; b0 += 64; b1 += 64;
    asm volatile("s_waitcnt vmcnt(4)" ::: "memory");   // step 0 landed
    __builtin_amdgcn_s_barrier();
    __builtin_amdgcn_sched_barrier(0);

    // body kk (BUF = kk%3): stage kk+2 -> (BUF+2)%3; 8 ds_read + 16 MFMA;
    // vmcnt(4)+barrier confirms step kk+1 for the next body.
#define GEMM_BODY(BUFI, DO_STAGE, WAITK) do {                                        \
        constexpr int BUF_ = (BUFI);                                                 \
        constexpr int TGT_ = (BUF_ + 2) % 3;                                         \
        if (DO_STAGE) {                                                              \
            async16(a0, &Sm[TGT_][ci0 * 512]);                                       \
            async16(b0, &Sm[TGT_][4096 + ci0 * 512]);                                \
            async16(a1, &Sm[TGT_][ci1 * 512]);                                       \
            async16(b1, &Sm[TGT_][4096 + ci1 * 512]);                                \
            a0 += 32; a1 += 32; b0 += 32; b1 += 32;                                  \
        }                                                                            \
        const char* Ab_ = (const char*)&Sm[BUF_][0];                                 \
        const char* Bb_ = (const char*)&Sm[BUF_][4096];                              \
        bf16x8 af[4], bg[4];                                                         \
        _Pragma("unroll")                                                            \
        for (int i = 0; i < 4; ++i)                                                  \
            af[i] = *(const bf16x8*)(Ab_ + (wr0 + i * 16 + lr) * 64 + ((lq ^ xr) * 16)); \
        _Pragma("unroll")                                                            \
        for (int j = 0; j < 4; ++j)                                                  \
            bg[j] = *(const bf16x8*)(Bb_ + (wc0 + j * 16 + lr) * 64 + ((lq ^ xr) * 16)); \
        _Pragma("unroll")                                                            \
        for (int i = 0; i < 4; ++i)                                                  \
            _Pragma("unroll")                                                        \
            for (int j = 0; j < 4; ++j)                                              \
                acc[i][j] = __builtin_amdgcn_mfma_f32_16x16x32_bf16(af[i], bg[j], acc[i][j], 0, 0, 0); \
        if ((WAITK) == 0) {                                                          \
            asm volatile("s_waitcnt vmcnt(4)" ::: "memory");                         \
            __builtin_amdgcn_s_barrier();                                            \
            __builtin_amdgcn_sched_barrier(0);                                       \
        } else if ((WAITK) == 1) {                                                   \
            asm volatile("s_waitcnt vmcnt(0)" ::: "memory");                         \
            __builtin_amdgcn_s_barrier();                                            \
            __builtin_amdgcn_sched_barrier(0);                                       \
        }                                                                            \
    } while (0)

    // kk = 0..29: ten groups of 3 (last stage at kk=29 targets step 31)
    for (int g = 0; g < 10; ++g) {
        GEMM_BODY(0, true, 0);
        GEMM_BODY(1, true, 0);
        GEMM_BODY(2, true, 0);
    }
    GEMM_BODY(0, false, 1);   // kk=30, drain (step 31 lands)
    GEMM_BODY(1, false, 2);   // kk=31, no barrier
#undef GEMM_BODY
}

// --------- QKV projection: X[4096,1024] @ W^T -> Q/K [B,H,S,D], V [B,H,D,S] ---
// Q output (z==0) pre-scaled by LOG2E so attention softmax is a raw exp2.
// z==2 (V): transpose fused into the epilogue -- acc tile staged to the dead
// 48KB Sm LDS (stride-129 pad: writes conflict-free, reads ~2-way), then V^T
// written with coalesced 16B stores. Replaces the standalone transpose_v
// kernel (saves 16MB HBM round-trip + a launch).
__global__ __launch_bounds__(256, 3)
void proj_gemm(const u16* __restrict__ Xq, const u16* __restrict__ Xk, const u16* __restrict__ Xv,
               const u16* __restrict__ Wq, const u16* __restrict__ Wk, const u16* __restrict__ Wv,
               u16* __restrict__ Qo, u16* __restrict__ Ko, u16* __restrict__ Vto)
{
    __shared__ __align__(16) u16 Sm[3][8192];   // 48KB: 3 bufs x [A 8KB | B 8KB]
    const u16* A; const u16* W; u16* C; float scale;
    if (blockIdx.z == 0)      { A = Xq; W = Wq; C = Qo;  scale = LOG2E; }
    else if (blockIdx.z == 1) { A = Xk; W = Wk; C = Ko;  scale = 1.0f; }
    else                      { A = Xv; W = Wv; C = Vto; scale = 1.0f; }

    f32x4 acc[4][4];
    gemm128_pipe3(A, W, blockIdx.y * 128, blockIdx.x * 128, Sm, acc);

    const int tid = threadIdx.x, w = tid >> 6, l = tid & 63;
    const int lr = l & 15, lq = l >> 4;
    if (blockIdx.z != 2) {
        // Q/K epilogue: [B,H,S,D] scatter (unchanged from R8)
        const int r0 = blockIdx.y * 128 + (w >> 1) * 64;
        const int c0 = blockIdx.x * 128 + (w & 1) * 64;
#pragma unroll
        for (int i = 0; i < 4; ++i)
#pragma unroll
            for (int j = 0; j < 4; ++j)
#pragma unroll
                for (int r = 0; r < 4; ++r) {
                    int row = r0 + i * 16 + lq * 4 + r;   // X row = s*2 + b
                    int col = c0 + j * 16 + lr;           // n = h*64 + d
                    int s = row >> 1, b = row & 1, h = col >> 6, d = col & 63;
                    C[(size_t)((b * 16 + h) * 2048 + s) * 64 + d] = f2bf(acc[i][j][r] * scale);
                }
    } else {
        // V epilogue: transpose via LDS, write [B,H,D,S].
        u16* Tm = &Sm[0][0];                 // [128][129] u16 = 33KB, fits 48KB
        __syncthreads();                     // all waves done with K-loop LDS reads
        const int rl0 = (w >> 1) * 64, cl0 = (w & 1) * 64;
#pragma unroll
        for (int i = 0; i < 4; ++i)
#pragma unroll
            for (int j = 0; j < 4; ++j)
#pragma unroll
                for (int r = 0; r < 4; ++r)
                    Tm[(rl0 + i * 16 + lq * 4 + r) * 129 + (cl0 + j * 16 + lr)] = f2bf(acc[i][j][r]);
        __syncthreads();
        // local row = sl*2 + b (sl = s - y*64), local col = hh*64 + d
        const int e = tid & 7, g = tid >> 3;
#pragma unroll
        for (int p = 0; p < 8; ++p) {
            int dr = p * 32 + g;                       // [0,256): (b, hh, d)
            int b = dr >> 7, hh = (dr >> 6) & 1, d = dr & 63;
            int h = blockIdx.x * 2 + hh;
            alignas(16) u16 tmp[8];
#pragma unroll
            for (int k = 0; k < 8; ++k)
                tmp[k] = Tm[((e * 8 + k) * 2 + b) * 129 + hh * 64 + d];
            *(uint4*)&C[((size_t)(b * 16 + h) * 64 + d) * 2048 + blockIdx.y * 64 + e * 8] =
                *(const uint4*)tmp;
        }
    }
}

// --------- flash attention v9 (R3/R6/R8-verified, 43.0us): quad-buffer, -------
// counted vmcnt, static addresses. 4 waves x 32 q-rows = Q-tile 128; KV tile
// 64; FOUR buffers (64KB LDS), prefetch 2 tiles ahead, one raw s_barrier per
// kt with s_waitcnt vmcnt(4) (never 0 in the main loop). Per-kt S[2] = {}
// init (Zf-seed costs +6us -- measured A/B R7 vs R8).
__global__ __launch_bounds__(256, 2)
void attn_kernel(const u16* __restrict__ Qg, const u16* __restrict__ Kg,
                 const u16* __restrict__ Vtg, u16* __restrict__ attn)
{
    __shared__ __align__(16) u16 KV[4][8192];      // [buf][ K tile 8KB | V^T tile 8KB ]

    const int tid = threadIdx.x, w = tid >> 6, l = tid & 63;
    const int q = l & 31, hi = l >> 5;
    const int swz = (q & 7) ^ ((q >> 3) & 3);       // read-side XOR (row bits 0..4)
    const int srow = l >> 3;

    // XCD-aware remap: grid 16x32 = 512 blocks; xcd = lin&7; 4 bh per xcd, 16 q-blocks/bh
    const int lin = blockIdx.x + (blockIdx.y << 4);   // gridDim.x == 16
    const int grp = lin >> 3;                          // [0,64)
    const int bh  = (lin & 7) * 4 + (grp >> 4);
    const int q0  = (grp & 15) * 128;
    const size_t base = (size_t)bh * 2048 * 64;

    // per-lane LDS read base (bytes): row q within a 64x64 tile, column slot kd
    int ra[4];
#pragma unroll
    for (int kd = 0; kd < 4; ++kd)
        ra[kd] = q * 128 + (((kd * 2 + hi) ^ swz) * 16);

    // prologue staging: Q(128x64 = 16KB) -> KV[3]; K0/V0 -> KV[0]; K1/V1 -> KV[1]
#pragma unroll
    for (int c = 0; c < 4; ++c) {
        int ci = w * 4 + c, row = ci * 8 + srow;
        int swcol = ((l & 7) ^ (l >> 3) ^ (ci & 3)) * 8;
        async16(&Qg[base + (size_t)(q0 + row) * 64 + swcol], &KV[3][ci * 512]);
    }
#pragma unroll
    for (int t = 0; t < 2; ++t)
#pragma unroll
        for (int c = 0; c < 2; ++c) {
            int ci = w * 2 + c, row = ci * 8 + srow;
            int swcol = ((l & 7) ^ (l >> 3) ^ (ci & 3)) * 8;
            async16(&Kg[base + (size_t)(t * 64 + row) * 64 + swcol], &KV[t][ci * 512]);
            async16(&Vtg[base + (size_t)row * 2048 + t * 64 + swcol], &KV[t][4096 + ci * 512]);
        }

    // walking staging pointers, positioned for tile 2
    const int row0 = (w * 2 + 0) * 8 + srow, row1 = (w * 2 + 1) * 8 + srow;
    const int sw0 = ((l & 7) ^ (l >> 3) ^ ((w * 2 + 0) & 3)) * 8;
    const int sw1 = ((l & 7) ^ (l >> 3) ^ ((w * 2 + 1) & 3)) * 8;
    const u16* kp0 = Kg + base + (size_t)(128 + row0) * 64 + sw0;
    const u16* kp1 = Kg + base + (size_t)(128 + row1) * 64 + sw1;
    const u16* vp0 = Vtg + base + (size_t)row0 * 2048 + 128 + sw0;
    const u16* vp1 = Vtg + base + (size_t)row1 * 2048 + 128 + sw1;

    // Q + K0/V0 landed (leaves K1/V1's 4 in flight); then block-wide visible
    asm volatile("s_waitcnt vmcnt(4)" ::: "memory");
    __builtin_amdgcn_s_barrier();
    __builtin_amdgcn_sched_barrier(0);

    // hoist Q fragments from KV[3]: row w*32+q, slot kd
    bf16x8 bq[4];
    {
        const char* Qb_ = (const char*)&KV[3][0];
#pragma unroll
        for (int kd = 0; kd < 4; ++kd)
            bq[kd] = *(const bf16x8*)(Qb_ + w * 4096 + ra[kd]);
    }

    f32x16 O[2] = {};  // O^T: [d-tile nt][q = lane&31]; d = nt*32 + (r&3)+8*(r>>2)+4*hi
    float l0 = 0.f, l1 = 0.f, l2 = 0.f, l3 = 0.f;

    // one kt step. BUFI static (kt&3); DO_ISSUE stages kt+2 into (BUFI+2)&3;
    // WAITK: 0 = vmcnt(4)+barrier, 1 = vmcnt(0)+barrier, 2 = none (last)
#define ATTN_STEP(BUFI, DO_ISSUE, WAITK) do {                                        \
        constexpr int BUF_ = (BUFI);                                                 \
        constexpr int TGT_ = (BUF_ + 2) & 3;                                         \
        if (DO_ISSUE) {                                                              \
            async16(kp0, &KV[TGT_][(w * 2 + 0) * 512]);                              \
            async16(vp0, &KV[TGT_][4096 + (w * 2 + 0) * 512]);                       \
            async16(kp1, &KV[TGT_][(w * 2 + 1) * 512]);                              \
            async16(vp1, &KV[TGT_][4096 + (w * 2 + 1) * 512]);                       \
            kp0 += 4096; kp1 += 4096; vp0 += 64; vp1 += 64;                          \
        }                                                                            \
        const char* Kb_ = (const char*)&KV[BUF_][0];                                 \
        const char* Vb_ = (const char*)&KV[BUF_][4096];                              \
        f32x16 S[2] = {};                                                            \
        _Pragma("unroll")                                                            \
        for (int mt = 0; mt < 2; ++mt)                                               \
            _Pragma("unroll")                                                        \
            for (int kd = 0; kd < 4; ++kd) {                                         \
                bf16x8 ak = *(const bf16x8*)(Kb_ + mt * 4096 + ra[kd]);              \
                S[mt] = __builtin_amdgcn_mfma_f32_32x32x16_bf16(ak, bq[kd], S[mt], 0, 0, 0); \
            }                                                                        \
        _Pragma("unroll")                                                            \
        for (int mt = 0; mt < 2; ++mt)                                               \
            _Pragma("unroll")                                                        \
            for (int r = 0; r < 16; r += 4) {                                        \
                S[mt][r+0] = __builtin_amdgcn_exp2f(S[mt][r+0]); l0 += S[mt][r+0];   \
                S[mt][r+1] = __builtin_amdgcn_exp2f(S[mt][r+1]); l1 += S[mt][r+1];   \
                S[mt][r+2] = __builtin_amdgcn_exp2f(S[mt][r+2]); l2 += S[mt][r+2];   \
                S[mt][r+3] = __builtin_amdgcn_exp2f(S[mt][r+3]); l3 += S[mt][r+3];   \
            }                                                                        \
        bf16x8 bp[4];                                                                \
        _Pragma("unroll")                                                            \
        for (int mt = 0; mt < 2; ++mt) {                                             \
            unsigned W0 = cvtpk(S[mt][0],  S[mt][1]);                                \
            unsigned W1 = cvtpk(S[mt][2],  S[mt][3]);                                \
            unsigned W2 = cvtpk(S[mt][4],  S[mt][5]);                                \
            unsigned W3 = cvtpk(S[mt][6],  S[mt][7]);                                \
            unsigned W4 = cvtpk(S[mt][8],  S[mt][9]);                                \
            unsigned W5 = cvtpk(S[mt][10], S[mt][11]);                               \
            unsigned W6 = cvtpk(S[mt][12], S[mt][13]);                               \
            unsigned W7 = cvtpk(S[mt][14], S[mt][15]);                               \
            auto a0 = plswap(W0, W2);                                                \
            auto a1 = plswap(W1, W3);                                                \
            auto a2 = plswap(W4, W6);                                                \
            auto a3 = plswap(W5, W7);                                                \
            u32x4 lo4 = {(unsigned)a0[0], (unsigned)a1[0], (unsigned)a0[1], (unsigned)a1[1]}; \
            u32x4 hi4 = {(unsigned)a2[0], (unsigned)a3[0], (unsigned)a2[1], (unsigned)a3[1]}; \
            bp[2*mt+0] = __builtin_bit_cast(bf16x8, lo4);                            \
            bp[2*mt+1] = __builtin_bit_cast(bf16x8, hi4);                            \
        }                                                                            \
        _Pragma("unroll")                                                            \
        for (int nt = 0; nt < 2; ++nt)                                               \
            _Pragma("unroll")                                                        \
            for (int ks = 0; ks < 4; ++ks) {                                         \
                bf16x8 av = *(const bf16x8*)(Vb_ + nt * 4096 + ra[ks]);              \
                O[nt] = __builtin_amdgcn_mfma_f32_32x32x16_bf16(av, bp[ks], O[nt], 0, 0, 0); \
            }                                                                        \
        if ((WAITK) == 0) {                                                          \
            asm volatile("s_waitcnt vmcnt(4)" ::: "memory");                         \
            __builtin_amdgcn_s_barrier();                                            \
            __builtin_amdgcn_sched_barrier(0);                                       \
        } else if ((WAITK) == 1) {                                                   \
            asm volatile("s_waitcnt vmcnt(0)" ::: "memory");                         \
            __builtin_amdgcn_s_barrier();                                            \
            __builtin_amdgcn_sched_barrier(0);                                       \
        }                                                                            \
    } while (0)

    for (int kt4 = 0; kt4 < 28; kt4 += 4) {
        ATTN_STEP(0, true, 0);
        ATTN_STEP(1, true, 0);
        ATTN_STEP(2, true, 0);
        ATTN_STEP(3, true, 0);
    }
    // tail: kt = 28..31 (kt=28 stages kt=30; kt=29 stages kt=31; then drain)
    ATTN_STEP(0, true, 0);
    ATTN_STEP(1, true, 0);
    ATTN_STEP(2, false, 1);
    ATTN_STEP(3, false, 2);
#undef ATTN_STEP

    // final softmax denominator: lane sum -> cross-half reduce (once, not per kt)
    float rs = (l0 + l1) + (l2 + l3);
    {
        auto t = plswap(__float_as_uint(rs), __float_as_uint(rs));
        rs = __uint_as_float((unsigned)t[0]) + __uint_as_float((unsigned)t[1]);
    }
    const float inv = 1.f / rs;

    // epilogue: lane holds q = l&31 -> s = q0 + w*32 + q; d = nt*32 + u*8 + hi*4 + e
    const int b = bh >> 4, h = bh & 15;
    const int s = q0 + w * 32 + q;
    u16* orow = &attn[(size_t)(s * 2 + b) * 1024 + h * 64];
#pragma unroll
    for (int nt = 0; nt < 2; ++nt)
#pragma unroll
        for (int u = 0; u < 4; ++u) {
            uint2 pk;
            pk.x = pack_rn(O[nt][4*u+0] * inv, O[nt][4*u+1] * inv);
            pk.y = pack_rn(O[nt][4*u+2] * inv, O[nt][4*u+3] * inv);
            *(uint2*)&orow[nt * 32 + u * 8 + hi * 4] = pk;
        }
}

// --------- output projection: attn[4096,1024] @ Wo^T -> fp32 out --------------
// 128x64 tile, 128 threads (2 waves), 3-buffer BK=32 counted-vmcnt pipe
// (same skeleton as gemm128_pipe3; 6 loads/body -> vmcnt(6)). LDS 36KB.
// R7/R8-verified.
__global__ __launch_bounds__(128)
void out_gemm(const u16* __restrict__ A, const u16* __restrict__ W, float* __restrict__ out)
{
    __shared__ __align__(16) u16 Sm[3][6144];   // 3 bufs x [A 8KB | B 4KB]
    const int tid = threadIdx.x;
    const int w = tid >> 6, l = tid & 63;
    const int lr = l & 15, lq = l >> 4;
    const int xr = (lr & 3) ^ ((lr >> 2) & 3);
    const int swc = ((l & 3) ^ ((l >> 2) & 3) ^ (l >> 4)) * 8;
    const int rowBase = blockIdx.y * 128;
    const int colBase = blockIdx.x * 64;

    const u16* ap0 = A + (size_t)(rowBase + (w * 4 + 0) * 16 + (l >> 2)) * 1024 + swc;
    const u16* ap1 = A + (size_t)(rowBase + (w * 4 + 1) * 16 + (l >> 2)) * 1024 + swc;
    const u16* ap2 = A + (size_t)(rowBase + (w * 4 + 2) * 16 + (l >> 2)) * 1024 + swc;
    const u16* ap3 = A + (size_t)(rowBase + (w * 4 + 3) * 16 + (l >> 2)) * 1024 + swc;
    const u16* bp0 = W + (size_t)(colBase + (w * 2 + 0) * 16 + (l >> 2)) * 1024 + swc;
    const u16* bp1 = W + (size_t)(colBase + (w * 2 + 1) * 16 + (l >> 2)) * 1024 + swc;

    f32x4 acc[4][4];
#pragma unroll
    for (int i = 0; i < 4; ++i)
#pragma unroll
        for (int j = 0; j < 4; ++j) acc[i][j] = (f32x4){0.f, 0.f, 0.f, 0.f};

    // prologue: stage K-steps 0 (buf0) and 1 (buf1); 12 loads/lane
    async16(ap0,      &Sm[0][(w * 4 + 0) * 512]);
    async16(ap1,      &Sm[0][(w * 4 + 1) * 512]);
    async16(ap2,      &Sm[0][(w * 4 + 2) * 512]);
    async16(ap3,      &Sm[0][(w * 4 + 3) * 512]);
    async16(bp0,      &Sm[0][4096 + (w * 2 + 0) * 512]);
    async16(bp1,      &Sm[0][4096 + (w * 2 + 1) * 512]);
    async16(ap0 + 32, &Sm[1][(w * 4 + 0) * 512]);
    async16(ap1 + 32, &Sm[1][(w * 4 + 1) * 512]);
    async16(ap2 + 32, &Sm[1][(w * 4 + 2) * 512]);
    async16(ap3 + 32, &Sm[1][(w * 4 + 3) * 512]);
    async16(bp0 + 32, &Sm[1][4096 + (w * 2 + 0) * 512]);
    async16(bp1 + 32, &Sm[1][4096 + (w * 2 + 1) * 512]);
    ap0 += 64; ap1 += 64; ap2 += 64; ap3 += 64; bp0 += 64; bp1 += 64;
    asm volatile("s_waitcnt vmcnt(6)" ::: "memory");   // step 0 landed
    __builtin_amdgcn_s_barrier();
    __builtin_amdgcn_sched_barrier(0);

#define OUT_BODY(BUFI, DO_STAGE, WAITK) do {                                         \
        constexpr int BUF_ = (BUFI);                                                 \
        constexpr int TGT_ = (BUF_ + 2) % 3;                                         \
        if (DO_STAGE) {                                                              \
            async16(ap0, &Sm[TGT_][(w * 4 + 0) * 512]);                              \
            async16(ap1, &Sm[TGT_][(w * 4 + 1) * 512]);                              \
            async16(ap2, &Sm[TGT_][(w * 4 + 2) * 512]);                              \
            async16(ap3, &Sm[TGT_][(w * 4 + 3) * 512]);                              \
            async16(bp0, &Sm[TGT_][4096 + (w * 2 + 0) * 512]);                       \
            async16(bp1, &Sm[TGT_][4096 + (w * 2 + 1) * 512]);                       \
            ap0 += 32; ap1 += 32; ap2 += 32; ap3 += 32; bp0 += 32; bp1 += 32;        \
        }                                                                            \
        const char* Ab_ = (const char*)&Sm[BUF_][0];                                 \
        const char* Bb_ = (const char*)&Sm[BUF_][4096];                              \
        bf16x8 af[4], bg[4];                                                         \
        _Pragma("unroll")                                                            \
        for (int i = 0; i < 4; ++i)                                                  \
            af[i] = *(const bf16x8*)(Ab_ + (w * 64 + i * 16 + lr) * 64 + ((lq ^ xr) * 16)); \
        _Pragma("unroll")                                                            \
        for (int j = 0; j < 4; ++j)                                                  \
            bg[j] = *(const bf16x8*)(Bb_ + (j * 16 + lr) * 64 + ((lq ^ xr) * 16));   \
        _Pragma("unroll")                                                            \
        for (int i = 0; i < 4; ++i)                                                  \
            _Pragma("unroll")                                                        \
            for (int j = 0; j < 4; ++j)                                              \
                acc[i][j] = __builtin_amdgcn_mfma_f32_16x16x32_bf16(af[i], bg[j], acc[i][j], 0, 0, 0); \
        if ((WAITK) == 0) {                                                          \
            asm volatile("s_waitcnt vmcnt(6)" ::: "memory");                         \
            __builtin_amdgcn_s_barrier();                                            \
            __builtin_amdgcn_sched_barrier(0);                                       \
        } else if ((WAITK) == 1) {                                                   \
            asm volatile("s_waitcnt vmcnt(0)" ::: "memory");                         \
            __builtin_amdgcn_s_barrier();                                            \
            __builtin_amdgcn_sched_barrier(0);                                       \
        }                                                                            \
    } while (0)

    for (int g = 0; g < 10; ++g) {
        OUT_BODY(0, true, 0);
        OUT_BODY(1, true, 0);
        OUT_BODY(2, true, 0);
    }
    OUT_BODY(0, false, 1);   // kk=30, drain (step 31 lands)
    OUT_BODY(1, false, 2);   // kk=31, no barrier
#undef OUT_BODY

    const int r0 = rowBase + w * 64;
#pragma unroll
    for (int i = 0; i < 4; ++i)
#pragma unroll
        for (int j = 0; j < 4; ++j)
#pragma unroll
            for (int r = 0; r < 4; ++r)
                out[(size_t)(r0 + i * 16 + lq * 4 + r) * 1024 + (colBase + j * 16 + lr)] = acc[i][j][r];
}

extern "C" void kernel_launch(void* const* d_in, const int* in_sizes, int n_in,
                              void* d_out, int out_size, void* d_ws, size_t ws_size,
                              hipStream_t stream)
{
    const float* q  = (const float*)d_in[0];
    const float* k  = (const float*)d_in[1];
    const float* v  = (const float*)d_in[2];
    const float* Wq = (const float*)d_in[3];
    const float* Wk = (const float*)d_in[4];
    const float* Wv = (const float*)d_in[5];
    const float* Wo = (const float*)d_in[6];

    // workspace layout (u16 elements); needs 58,720,256 bytes.
    u16* ws   = (u16*)d_ws;
    u16* Xq   = ws;              // 4M elems
    u16* Xk   = ws + 4194304;
    u16* Xv   = ws + 8388608;
    u16* Wqb  = ws + 12582912;   // 1M each
    u16* Wkb  = ws + 13631488;
    u16* Wvb  = ws + 14680064;
    u16* Wob  = ws + 15728640;
    u16* Qb   = ws + 16777216;   // 4M each
    u16* Kb   = ws + 20971520;
    u16* Vt   = ws + 25165824;   // V^T [B,H,D,S], written directly by proj_gemm
    u16* At   = Xk;   // alias: Xk dead after proj_gemm

    convert_all<<<dim3(512, 1, 7), 256, 0, stream>>>(q, k, v, Wq, Wk, Wv, Wo,
                                                     Xq, Xk, Xv, Wqb, Wkb, Wvb, Wob);
    proj_gemm<<<dim3(8, 32, 3), 256, 0, stream>>>(Xq, Xk, Xv, Wqb, Wkb, Wvb, Qb, Kb, Vt);
    attn_kernel<<<dim3(16, 32), 256, 0, stream>>>(Qb, Kb, Vt, At);
    out_gemm<<<dim3(16, 32), 128, 0, stream>>>(At, Wob, (float*)d_out);
}